// Round 2
// baseline (982.448 us; speedup 1.0000x reference)
//
#include <hip/hip_runtime.h>

#define FIN 128
#define C1 64
#define C2 32
#define BN_EPS 1e-5f

// ---------------- degree ----------------
__global__ __launch_bounds__(256) void k_deg(const int* __restrict__ ei, const float* __restrict__ ew,
                                             float* __restrict__ deg, int E) {
  int e = blockIdx.x * 256 + threadIdx.x;
  if (e < E) atomicAdd(&deg[ei[E + e]], ew[e]);
}

__global__ __launch_bounds__(256) void k_dinv(float* __restrict__ deg, int N) {
  int i = blockIdx.x * 256 + threadIdx.x;
  if (i < N) deg[i] = rsqrtf(deg[i] + 1.0f);  // dinv = 1/sqrt(deg+1); 1/deg = dinv*dinv
}

// ---------------- xw1 = x @ W1  (128 -> 64) ----------------
__global__ __launch_bounds__(256) void k_gemm1(const float* __restrict__ x, const float* __restrict__ W1,
                                               float* __restrict__ xw1, int N) {
  __shared__ float Ws[FIN * C1];  // 32 KB
  for (int t = threadIdx.x; t < FIN * C1; t += 256) Ws[t] = W1[t];
  __syncthreads();
  const int lane = threadIdx.x & 63;
  const int wid = (blockIdx.x * 256 + threadIdx.x) >> 6;
  const int nw = (gridDim.x * 256) >> 6;
  for (int row = wid; row < N; row += nw) {
    const float* xr = x + (size_t)row * FIN;
    float x0 = xr[lane];
    float x1 = xr[64 + lane];
    float acc = 0.f;
#pragma unroll
    for (int k = 0; k < 64; ++k) acc = fmaf(__shfl(x0, k), Ws[k * C1 + lane], acc);
#pragma unroll
    for (int k = 0; k < 64; ++k) acc = fmaf(__shfl(x1, k), Ws[(64 + k) * C1 + lane], acc);
    xw1[(size_t)row * C1 + lane] = acc;
  }
}

// ---------------- self-loop init: agg = xw * dinv^2 + b ----------------
template <int C>
__global__ __launch_bounds__(256) void k_selfloop(const float* __restrict__ xw, const float* __restrict__ dinv,
                                                  const float* __restrict__ b, float* __restrict__ agg, int N) {
  int total = N * C;
  for (int t = blockIdx.x * 256 + threadIdx.x; t < total; t += gridDim.x * 256) {
    int i = t / C, j = t % C;
    float dv = dinv[i];
    agg[t] = fmaf(xw[t], dv * dv, b[j]);
  }
}

// ---------------- edge aggregation, layer 1: one wave per edge (64 feats) ----------------
__global__ __launch_bounds__(256) void k_edge1(const int* __restrict__ ei, const float* __restrict__ ew,
                                               const float* __restrict__ dinv, const float* __restrict__ xw,
                                               float* __restrict__ agg, int E) {
  const int lane = threadIdx.x & 63;
  const int wid = (blockIdx.x * 256 + threadIdx.x) >> 6;
  const int nw = (gridDim.x * 256) >> 6;
  for (int e = wid; e < E; e += nw) {
    int src = ei[e];
    int dst = ei[E + e];
    float nrm = dinv[src] * ew[e] * dinv[dst];
    atomicAdd(&agg[(size_t)dst * C1 + lane], xw[(size_t)src * C1 + lane] * nrm);
  }
}

// ---------------- edge aggregation, layer 2: two edges per wave (32 feats) ----------------
__global__ __launch_bounds__(256) void k_edge2(const int* __restrict__ ei, const float* __restrict__ ew,
                                               const float* __restrict__ dinv, const float* __restrict__ xw,
                                               float* __restrict__ agg, int E) {
  const int lane = threadIdx.x & 63;
  const int j = lane & 31, sub = lane >> 5;
  const int wid = (blockIdx.x * 256 + threadIdx.x) >> 6;
  const int nw = (gridDim.x * 256) >> 6;
  for (int e = wid * 2 + sub; e < E; e += nw * 2) {
    int src = ei[e];
    int dst = ei[E + e];
    float nrm = dinv[src] * ew[e] * dinv[dst];
    atomicAdd(&agg[(size_t)dst * C2 + j], xw[(size_t)src * C2 + j] * nrm);
  }
}

// ---------------- BN stats: per-column sum & sumsq ----------------
template <int C>
__global__ __launch_bounds__(256) void k_bnstats(const float* __restrict__ h, float* __restrict__ stat, int N) {
  const int rpb = 256 / C;
  const int j = threadIdx.x % C;
  const int rloc = threadIdx.x / C;
  float s = 0.f, sq = 0.f;
  for (int r = blockIdx.x * rpb + rloc; r < N; r += gridDim.x * rpb) {
    float v = h[(size_t)r * C + j];
    s += v;
    sq = fmaf(v, v, sq);
  }
  __shared__ float ls[256], lq[256];
  ls[threadIdx.x] = s;
  lq[threadIdx.x] = sq;
  __syncthreads();
  if (threadIdx.x < C) {
    float ts = 0.f, tq = 0.f;
#pragma unroll
    for (int k = 0; k < rpb; ++k) {
      ts += ls[k * C + j];
      tq += lq[k * C + j];
    }
    atomicAdd(&stat[j], ts);
    atomicAdd(&stat[C + j], tq);
  }
}

template <int C>
__global__ void k_bnfinal(const float* __restrict__ stat, const float* __restrict__ g,
                          const float* __restrict__ be, float* __restrict__ ss, int N) {
  int j = threadIdx.x;
  if (j < C) {
    float inv_n = 1.0f / (float)N;
    float mean = stat[j] * inv_n;
    float var = stat[C + j] * inv_n - mean * mean;
    float sc = g[j] * rsqrtf(var + BN_EPS);
    ss[j] = sc;
    ss[C + j] = be[j] - mean * sc;
  }
}

// ---------------- BN apply + ReLU (in place) ----------------
template <int C>
__global__ __launch_bounds__(256) void k_bnapply(float* __restrict__ h, const float* __restrict__ ss, int N) {
  int total = N * C;
  for (int t = blockIdx.x * 256 + threadIdx.x; t < total; t += gridDim.x * 256) {
    int j = t % C;
    float v = fmaf(h[t], ss[j], ss[C + j]);
    h[t] = v > 0.f ? v : 0.f;
  }
}

// ---------------- xw2 = h1 @ W2  (64 -> 32), two rows per wave ----------------
__global__ __launch_bounds__(256) void k_gemm2(const float* __restrict__ h1, const float* __restrict__ W2,
                                               float* __restrict__ xw2, int N) {
  __shared__ float Ws[C1 * C2];  // 8 KB
  for (int t = threadIdx.x; t < C1 * C2; t += 256) Ws[t] = W2[t];
  __syncthreads();
  const int lane = threadIdx.x & 63;
  const int c = lane & 31, half = lane >> 5;
  const int wid = (blockIdx.x * 256 + threadIdx.x) >> 6;
  const int nw = (gridDim.x * 256) >> 6;
  for (int r0 = wid * 2; r0 < N; r0 += nw * 2) {
    int r1 = (r0 + 1 < N) ? r0 + 1 : r0;
    float hA = h1[(size_t)r0 * C1 + lane];
    float hB = h1[(size_t)r1 * C1 + lane];
    float acc = 0.f;
#pragma unroll
    for (int k = 0; k < C1; ++k) {
      float va = __shfl(hA, k);
      float vb = __shfl(hB, k);
      acc = fmaf(half ? vb : va, Ws[k * C2 + c], acc);
    }
    int row = half ? r1 : r0;
    xw2[(size_t)row * C2 + c] = acc;
  }
}

// ---------------- head: out = h2 @ Wl + bl ----------------
__global__ __launch_bounds__(256) void k_head(const float* __restrict__ h2, const float* __restrict__ Wl,
                                              const float* __restrict__ bl, float* __restrict__ out, int N) {
  const int lane = threadIdx.x & 63;
  const int j = lane & 31, sub = lane >> 5;
  const int wid = (blockIdx.x * 256 + threadIdx.x) >> 6;
  const int nw = (gridDim.x * 256) >> 6;
  float wv = Wl[j];
  float blv = bl[0];
  for (int r0 = wid * 2; r0 < N; r0 += nw * 2) {
    int row = r0 + sub;
    float v = (row < N) ? h2[(size_t)row * C2 + j] * wv : 0.f;
    v += __shfl_down(v, 16, 32);
    v += __shfl_down(v, 8, 32);
    v += __shfl_down(v, 4, 32);
    v += __shfl_down(v, 2, 32);
    v += __shfl_down(v, 1, 32);
    if (j == 0 && row < N) out[row] = v + blv;
  }
}

extern "C" void kernel_launch(void* const* d_in, const int* in_sizes, int n_in,
                              void* d_out, int out_size, void* d_ws, size_t ws_size,
                              hipStream_t stream) {
  const float* x = (const float*)d_in[0];
  const int* ei = (const int*)d_in[1];  // harness converts integer inputs to int32; [2, E] flat
  const float* ew = (const float*)d_in[2];
  const float* W1 = (const float*)d_in[3];
  const float* b1 = (const float*)d_in[4];
  const float* g1 = (const float*)d_in[5];
  const float* be1 = (const float*)d_in[6];
  const float* W2 = (const float*)d_in[7];
  const float* b2 = (const float*)d_in[8];
  const float* g2 = (const float*)d_in[9];
  const float* be2 = (const float*)d_in[10];
  const float* Wl = (const float*)d_in[11];
  const float* bl = (const float*)d_in[12];
  float* out = (float*)d_out;

  const int N = in_sizes[0] / FIN;
  const int E = in_sizes[2];

  // workspace layout (floats) — layer-2 buffers alias the xw1 region (free after gemm2 input h1 is built)
  float* W = (float*)d_ws;
  float* dinv = W;                    // [N]
  float* stat1 = W + N;               // [128] sum,sumsq
  float* ss1 = W + N + 128;           // [128] scale,shift
  float* stat2 = W + N + 256;         // [64]
  float* ss2 = W + N + 320;           // [64]
  float* bufA = W + N + 512;          // [N*64]  xw1, later xw2|h2
  float* bufB = bufA + (size_t)N * C1; // [N*64]  h1
  float* xw1 = bufA;
  float* h1 = bufB;
  float* xw2 = bufA;                  // [N*32]
  float* h2 = bufA + (size_t)N * C2;  // [N*32]

  // zero deg + stats accumulators (ws is poisoned 0xAA before every launch)
  hipMemsetAsync(W, 0, (size_t)(N + 512) * sizeof(float), stream);

  k_deg<<<(E + 255) / 256, 256, 0, stream>>>(ei, ew, dinv, E);
  k_dinv<<<(N + 255) / 256, 256, 0, stream>>>(dinv, N);

  // layer 1
  k_gemm1<<<2048, 256, 0, stream>>>(x, W1, xw1, N);
  k_selfloop<C1><<<4096, 256, 0, stream>>>(xw1, dinv, b1, h1, N);
  k_edge1<<<8192, 256, 0, stream>>>(ei, ew, dinv, xw1, h1, E);
  k_bnstats<C1><<<1024, 256, 0, stream>>>(h1, stat1, N);
  k_bnfinal<C1><<<1, C1, 0, stream>>>(stat1, g1, be1, ss1, N);
  k_bnapply<C1><<<4096, 256, 0, stream>>>(h1, ss1, N);

  // layer 2
  k_gemm2<<<2048, 256, 0, stream>>>(h1, W2, xw2, N);
  k_selfloop<C2><<<2048, 256, 0, stream>>>(xw2, dinv, b2, h2, N);
  k_edge2<<<8192, 256, 0, stream>>>(ei, ew, dinv, xw2, h2, E);
  k_bnstats<C2><<<1024, 256, 0, stream>>>(h2, stat2, N);
  k_bnfinal<C2><<<1, C2, 0, stream>>>(stat2, g2, be2, ss2, N);
  k_bnapply<C2><<<2048, 256, 0, stream>>>(h2, ss2, N);

  // head
  k_head<<<2048, 256, 0, stream>>>(h2, Wl, bl, out, N);
}

// Round 7
// 851.748 us; speedup vs baseline: 1.1534x; 1.1534x over previous
//
#include <hip/hip_runtime.h>
#include <hip/hip_bf16.h>

#define FIN 128
#define C1 64
#define C2 32
#define BN_EPS 1e-5f
#define CAP 28       // padded CSR slots per dst (Poisson(16) tail beyond 28 -> overflow list)
#define OVFCAP 65536 // overflow edge capacity (expected ~400 used)

typedef __hip_bfloat16 bf16;

// ---------------- weighted degree ----------------
__global__ __launch_bounds__(256) void k_deg(const int* __restrict__ ei, const float* __restrict__ ew,
                                             float* __restrict__ deg, int E) {
  int e = blockIdx.x * 256 + threadIdx.x;
  if (e < E) atomicAdd(&deg[ei[E + e]], ew[e]);
}

__global__ __launch_bounds__(256) void k_dinv(float* __restrict__ deg, int N) {
  int i = blockIdx.x * 256 + threadIdx.x;
  if (i < N) deg[i] = rsqrtf(deg[i] + 1.0f);  // dinv; 1/deg = dinv*dinv
}

// ---------------- padded CSR fill: fixed disjoint ranges, overflow to list ----------------
__global__ __launch_bounds__(256) void k_fillpad(const int* __restrict__ ei, int* __restrict__ pcnt,
                                                 int* __restrict__ pad, int* __restrict__ ovf,
                                                 int* __restrict__ ovfn, int E) {
  int e = blockIdx.x * 256 + threadIdx.x;
  if (e < E) {
    int dst = ei[E + e];
    int pos = atomicAdd(&pcnt[dst], 1);
    if (pos < CAP) {
      pad[(size_t)dst * CAP + pos] = e;
    } else {
      int oi = atomicAdd(ovfn, 1);
      if (oi < OVFCAP) ovf[oi] = e;
    }
  }
}

// ---------------- xw1 = x @ W1  (128 -> 64), bf16 output ----------------
__global__ __launch_bounds__(256) void k_gemm1(const float* __restrict__ x, const float* __restrict__ W1,
                                               bf16* __restrict__ xw1, int N) {
  __shared__ float Ws[FIN * C1];  // 32 KB
  for (int t = threadIdx.x; t < FIN * C1; t += 256) Ws[t] = W1[t];
  __syncthreads();
  const int lane = threadIdx.x & 63;
  const int wid = (blockIdx.x * 256 + threadIdx.x) >> 6;
  const int nw = (gridDim.x * 256) >> 6;
  for (int row = wid; row < N; row += nw) {
    const float* xr = x + (size_t)row * FIN;
    float x0 = xr[lane];
    float x1 = xr[64 + lane];
    float acc = 0.f;
#pragma unroll
    for (int k = 0; k < 64; ++k) acc = fmaf(__shfl(x0, k), Ws[k * C1 + lane], acc);
#pragma unroll
    for (int k = 0; k < 64; ++k) acc = fmaf(__shfl(x1, k), Ws[(64 + k) * C1 + lane], acc);
    xw1[(size_t)row * C1 + lane] = __float2bfloat16(acc);
  }
}

// ---------------- layer-1 aggregation: wave per dst, padded slots (c <= CAP <= 64: single batch) ----------------
__global__ __launch_bounds__(256) void k_agg1(const int* __restrict__ pcnt, const int* __restrict__ pad,
                                              const int* __restrict__ ei, const float* __restrict__ ew,
                                              const float* __restrict__ dinv, const bf16* __restrict__ xw,
                                              const float* __restrict__ b, float* __restrict__ h, int N, int E) {
  const int lane = threadIdx.x & 63;
  const int wid = (blockIdx.x * 256 + threadIdx.x) >> 6;
  const int nw = (gridDim.x * 256) >> 6;
  for (int dst = wid; dst < N; dst += nw) {
    float dv = dinv[dst];
    float acc = fmaf(__bfloat162float(xw[(size_t)dst * C1 + lane]), dv * dv, b[lane]);  // self + bias
    int c = pcnt[dst];
    c = c < CAP ? c : CAP;
    int sv = 0;
    float nv = 0.f;
    if (lane < c) {
      int eid = pad[(size_t)dst * CAP + lane];
      sv = ei[eid];
      nv = dinv[sv] * ew[eid] * dv;  // fp32 norm
    }
    for (int k = 0; k < c; ++k) {
      int s = __shfl(sv, k);
      float nm = __shfl(nv, k);
      acc = fmaf(__bfloat162float(xw[(size_t)s * C1 + lane]), nm, acc);
    }
    h[(size_t)dst * C1 + lane] = acc;
  }
}

// ---------------- layer-1 overflow edges: round-2-proven atomic pattern (~hundreds of edges) ----------------
__global__ __launch_bounds__(256) void k_ovf1(const int* __restrict__ ovf, const int* __restrict__ ovfn,
                                              const int* __restrict__ ei, const float* __restrict__ ew,
                                              const float* __restrict__ dinv, const bf16* __restrict__ xw,
                                              float* __restrict__ h, int E) {
  const int lane = threadIdx.x & 63;
  const int wid = (blockIdx.x * 256 + threadIdx.x) >> 6;
  const int nw = (gridDim.x * 256) >> 6;
  int n = ovfn[0];
  n = n < OVFCAP ? n : OVFCAP;
  for (int i = wid; i < n; i += nw) {
    int eid = ovf[i];
    int src = ei[eid];
    int dst = ei[E + eid];
    float nrm = dinv[src] * ew[eid] * dinv[dst];
    atomicAdd(&h[(size_t)dst * C1 + lane], __bfloat162float(xw[(size_t)src * C1 + lane]) * nrm);
  }
}

// ---------------- layer-2 aggregation: wave per dst, 32 feats x 2 edge-halves ----------------
__global__ __launch_bounds__(256) void k_agg2(const int* __restrict__ pcnt, const int* __restrict__ pad,
                                              const int* __restrict__ ei, const float* __restrict__ ew,
                                              const float* __restrict__ dinv, const float* __restrict__ xw,
                                              const float* __restrict__ b, float* __restrict__ h, int N, int E) {
  const int lane = threadIdx.x & 63;
  const int j = lane & 31, sub = lane >> 5;
  const int wid = (blockIdx.x * 256 + threadIdx.x) >> 6;
  const int nw = (gridDim.x * 256) >> 6;
  for (int dst = wid; dst < N; dst += nw) {
    float dv = dinv[dst];
    float acc = (sub == 0) ? fmaf(xw[(size_t)dst * C2 + j], dv * dv, b[j]) : 0.f;
    int c = pcnt[dst];
    c = c < CAP ? c : CAP;
    int sv = 0;
    float nv = 0.f;
    if (lane < c) {
      int eid = pad[(size_t)dst * CAP + lane];
      sv = ei[eid];
      nv = dinv[sv] * ew[eid] * dv;
    }
    for (int k = sub; k < c; k += 2) {
      int s = __shfl(sv, k);
      float nm = __shfl(nv, k);
      acc = fmaf(xw[(size_t)s * C2 + j], nm, acc);
    }
    acc += __shfl_xor(acc, 32);
    if (sub == 0) h[(size_t)dst * C2 + j] = acc;
  }
}

// ---------------- layer-2 overflow edges ----------------
__global__ __launch_bounds__(256) void k_ovf2(const int* __restrict__ ovf, const int* __restrict__ ovfn,
                                              const int* __restrict__ ei, const float* __restrict__ ew,
                                              const float* __restrict__ dinv, const float* __restrict__ xw,
                                              float* __restrict__ h, int E) {
  const int lane = threadIdx.x & 63;
  const int wid = (blockIdx.x * 256 + threadIdx.x) >> 6;
  const int nw = (gridDim.x * 256) >> 6;
  int n = ovfn[0];
  n = n < OVFCAP ? n : OVFCAP;
  for (int i = wid; i < n; i += nw) {
    int eid = ovf[i];
    int src = ei[eid];
    int dst = ei[E + eid];
    float nrm = dinv[src] * ew[eid] * dinv[dst];
    if (lane < C2) atomicAdd(&h[(size_t)dst * C2 + lane], xw[(size_t)src * C2 + lane] * nrm);
  }
}

// ---------------- BN stats: per-column sum & sumsq ----------------
template <int C>
__global__ __launch_bounds__(256) void k_bnstats(const float* __restrict__ h, float* __restrict__ stat, int N) {
  const int rpb = 256 / C;
  const int j = threadIdx.x % C;
  const int rloc = threadIdx.x / C;
  float s = 0.f, sq = 0.f;
  for (int r = blockIdx.x * rpb + rloc; r < N; r += gridDim.x * rpb) {
    float v = h[(size_t)r * C + j];
    s += v;
    sq = fmaf(v, v, sq);
  }
  __shared__ float ls[256], lq[256];
  ls[threadIdx.x] = s;
  lq[threadIdx.x] = sq;
  __syncthreads();
  if (threadIdx.x < C) {
    float ts = 0.f, tq = 0.f;
#pragma unroll
    for (int k = 0; k < rpb; ++k) {
      ts += ls[k * C + j];
      tq += lq[k * C + j];
    }
    atomicAdd(&stat[j], ts);
    atomicAdd(&stat[C + j], tq);
  }
}

template <int C>
__global__ void k_bnfinal(const float* __restrict__ stat, const float* __restrict__ g,
                          const float* __restrict__ be, float* __restrict__ ss, int N) {
  int j = threadIdx.x;
  if (j < C) {
    float inv_n = 1.0f / (float)N;
    float mean = stat[j] * inv_n;
    float var = stat[C + j] * inv_n - mean * mean;
    float sc = g[j] * rsqrtf(var + BN_EPS);
    ss[j] = sc;
    ss[C + j] = be[j] - mean * sc;
  }
}

// ---------------- BN apply + ReLU (in place) — round-2 proven ----------------
template <int C>
__global__ __launch_bounds__(256) void k_bnapply(float* __restrict__ h, const float* __restrict__ ss, int N) {
  int total = N * C;
  for (int t = blockIdx.x * 256 + threadIdx.x; t < total; t += gridDim.x * 256) {
    int j = t % C;
    float v = fmaf(h[t], ss[j], ss[C + j]);
    h[t] = v > 0.f ? v : 0.f;
  }
}

// ---------------- xw2 = h1 @ W2  (64 -> 32), two rows per wave — round-2 proven ----------------
__global__ __launch_bounds__(256) void k_gemm2(const float* __restrict__ h1, const float* __restrict__ W2,
                                               float* __restrict__ xw2, int N) {
  __shared__ float Ws[C1 * C2];  // 8 KB
  for (int t = threadIdx.x; t < C1 * C2; t += 256) Ws[t] = W2[t];
  __syncthreads();
  const int lane = threadIdx.x & 63;
  const int c = lane & 31, half = lane >> 5;
  const int wid = (blockIdx.x * 256 + threadIdx.x) >> 6;
  const int nw = (gridDim.x * 256) >> 6;
  for (int r0 = wid * 2; r0 < N; r0 += nw * 2) {
    int r1 = (r0 + 1 < N) ? r0 + 1 : r0;
    float hA = h1[(size_t)r0 * C1 + lane];
    float hB = h1[(size_t)r1 * C1 + lane];
    float acc = 0.f;
#pragma unroll
    for (int k = 0; k < C1; ++k) {
      float va = __shfl(hA, k);
      float vb = __shfl(hB, k);
      acc = fmaf(half ? vb : va, Ws[k * C2 + c], acc);
    }
    int row = half ? r1 : r0;
    xw2[(size_t)row * C2 + c] = acc;
  }
}

// ---------------- head: out = h2 @ Wl + bl — round-2 proven ----------------
__global__ __launch_bounds__(256) void k_head(const float* __restrict__ h2, const float* __restrict__ Wl,
                                              const float* __restrict__ bl, float* __restrict__ out, int N) {
  const int lane = threadIdx.x & 63;
  const int j = lane & 31, sub = lane >> 5;
  const int wid = (blockIdx.x * 256 + threadIdx.x) >> 6;
  const int nw = (gridDim.x * 256) >> 6;
  float wv = Wl[j];
  float blv = bl[0];
  for (int r0 = wid * 2; r0 < N; r0 += nw * 2) {
    int row = r0 + sub;
    float v = (row < N) ? h2[(size_t)row * C2 + j] * wv : 0.f;
    v += __shfl_down(v, 16, 32);
    v += __shfl_down(v, 8, 32);
    v += __shfl_down(v, 4, 32);
    v += __shfl_down(v, 2, 32);
    v += __shfl_down(v, 1, 32);
    if (j == 0 && row < N) out[row] = v + blv;
  }
}

extern "C" void kernel_launch(void* const* d_in, const int* in_sizes, int n_in,
                              void* d_out, int out_size, void* d_ws, size_t ws_size,
                              hipStream_t stream) {
  const float* x = (const float*)d_in[0];
  const int* ei = (const int*)d_in[1];  // int32 [2, E] flat
  const float* ew = (const float*)d_in[2];
  const float* W1 = (const float*)d_in[3];
  const float* b1 = (const float*)d_in[4];
  const float* g1 = (const float*)d_in[5];
  const float* be1 = (const float*)d_in[6];
  const float* W2 = (const float*)d_in[7];
  const float* b2 = (const float*)d_in[8];
  const float* g2 = (const float*)d_in[9];
  const float* be2 = (const float*)d_in[10];
  const float* Wl = (const float*)d_in[11];
  const float* bl = (const float*)d_in[12];
  float* out = (float*)d_out;

  const int N = in_sizes[0] / FIN;
  const int E = in_sizes[2];

  // workspace layout — 2N+512 header + OVFCAP + 28N + 32N + 64N floats ≈ 50.7 MB @ N=100k (< 51.6 proven)
  float* Wf = (float*)d_ws;
  float* dinv = Wf;                               // [N] f32
  int* pcnt = (int*)(Wf + N);                     // [N] i32 (atomic slot counters)
  int* ovfn = (int*)(Wf + 2 * (size_t)N);         // [1] i32
  float* stat1 = Wf + 2 * (size_t)N + 8;          // [128]
  float* ss1 = stat1 + 128;                       // [128]
  float* stat2 = ss1 + 128;                       // [64]
  float* ss2 = stat2 + 64;                        // [64]
  int* ovf = (int*)(Wf + 2 * (size_t)N + 512);    // [OVFCAP] i32
  int* pad = ovf + OVFCAP;                        // [N*CAP] i32 (fixed disjoint slot ranges)
  bf16* xw1 = (bf16*)(pad + (size_t)N * CAP);     // [N*64] bf16
  float* bufB = (float*)(xw1 + (size_t)N * C1);   // [N*64] f32
  float* h1 = bufB;
  float* xw2 = (float*)xw1;                       // [N*32] f32 — exact overlay of dead xw1
  float* h2 = bufB;                               // [N*32] f32 — overlays dead h1

  // zero: dinv + pcnt + ovfn + stats (one contiguous region)
  hipMemsetAsync(Wf, 0, ((size_t)2 * N + 512) * sizeof(float), stream);

  // build padded CSR (no scan — slot ranges disjoint by construction)
  k_deg<<<(E + 255) / 256, 256, 0, stream>>>(ei, ew, dinv, E);
  k_dinv<<<(N + 255) / 256, 256, 0, stream>>>(dinv, N);
  k_fillpad<<<(E + 255) / 256, 256, 0, stream>>>(ei, pcnt, pad, ovf, ovfn, E);

  // layer 1
  k_gemm1<<<2048, 256, 0, stream>>>(x, W1, xw1, N);
  k_agg1<<<4096, 256, 0, stream>>>(pcnt, pad, ei, ew, dinv, xw1, b1, h1, N, E);
  k_ovf1<<<256, 256, 0, stream>>>(ovf, ovfn, ei, ew, dinv, xw1, h1, E);
  k_bnstats<C1><<<1024, 256, 0, stream>>>(h1, stat1, N);
  k_bnfinal<C1><<<1, C1, 0, stream>>>(stat1, g1, be1, ss1, N);
  k_bnapply<C1><<<4096, 256, 0, stream>>>(h1, ss1, N);

  // layer 2
  k_gemm2<<<2048, 256, 0, stream>>>(h1, W2, xw2, N);
  k_agg2<<<2048, 256, 0, stream>>>(pcnt, pad, ei, ew, dinv, xw2, b2, h2, N, E);
  k_ovf2<<<256, 256, 0, stream>>>(ovf, ovfn, ei, ew, dinv, xw2, h2, E);
  k_bnstats<C2><<<1024, 256, 0, stream>>>(h2, stat2, N);
  k_bnfinal<C2><<<1, C2, 0, stream>>>(stat2, g2, be2, ss2, N);
  k_bnapply<C2><<<2048, 256, 0, stream>>>(h2, ss2, N);

  // head
  k_head<<<1024, 256, 0, stream>>>(h2, Wl, bl, out, N);
}

// Round 8
// 663.090 us; speedup vs baseline: 1.4816x; 1.2845x over previous
//
#include <hip/hip_runtime.h>
#include <hip/hip_bf16.h>

#define FIN 128
#define C1 64
#define C2 32
#define BN_EPS 1e-5f
#define CAP 28       // padded CSR slots per dst
#define OVFCAP 65536 // overflow edge capacity
#define R1 16        // rows per block-iter in gemm1
#define R2 16        // rows per block-iter in gemm2

typedef __hip_bfloat16 bf16;

// ---------------- fused: weighted degree + padded CSR fill ----------------
__global__ __launch_bounds__(256) void k_degfill(const int* __restrict__ ei, const float* __restrict__ ew,
                                                 float* __restrict__ deg, int* __restrict__ pcnt,
                                                 int* __restrict__ pad, int* __restrict__ ovf,
                                                 int* __restrict__ ovfn, int E) {
  int e = blockIdx.x * 256 + threadIdx.x;
  if (e < E) {
    int dst = ei[E + e];
    atomicAdd(&deg[dst], ew[e]);
    int pos = atomicAdd(&pcnt[dst], 1);
    if (pos < CAP) {
      pad[(size_t)dst * CAP + pos] = e;
    } else {
      int oi = atomicAdd(ovfn, 1);
      if (oi < OVFCAP) ovf[oi] = e;
    }
  }
}

__global__ __launch_bounds__(256) void k_dinv(float* __restrict__ deg, int N) {
  int i = blockIdx.x * 256 + threadIdx.x;
  if (i < N) deg[i] = rsqrtf(deg[i] + 1.0f);  // dinv; 1/deg = dinv*dinv
}

// ---------------- xw1 = x @ W1 (128 -> 64), W in regs (k-split by wave), bf16 out ----------------
__global__ __launch_bounds__(256) void k_gemm1(const float* __restrict__ x, const float* __restrict__ W1,
                                               bf16* __restrict__ xw1, int N) {
  const int lane = threadIdx.x & 63;
  const int w = threadIdx.x >> 6;  // wave id: owns k in [32w, 32w+32)
  float wr[32];
#pragma unroll
  for (int kk = 0; kk < 32; ++kk) wr[kk] = W1[(32 * w + kk) * C1 + lane];
  __shared__ float xs[R1][FIN];      // 8 KB
  __shared__ float part[R1][4][C1];  // 16 KB
  for (int base = blockIdx.x * R1; base < N; base += gridDim.x * R1) {
    int nrows = min(R1, N - base);
    __syncthreads();  // protect xs/part from previous iteration's readers
    for (int t = threadIdx.x; t < nrows * FIN; t += 256) {
      int r = t >> 7, k = t & 127;
      xs[r][k] = x[(size_t)(base + r) * FIN + k];
    }
    __syncthreads();
#pragma unroll 4
    for (int r = 0; r < R1; ++r) {
      if (r >= nrows) break;
      const float* xrow = &xs[r][32 * w];
      float acc = 0.f;
#pragma unroll
      for (int kk = 0; kk < 32; kk += 4) {
        float4 xv = *(const float4*)&xrow[kk];  // uniform-address b128 broadcast
        acc = fmaf(xv.x, wr[kk], acc);
        acc = fmaf(xv.y, wr[kk + 1], acc);
        acc = fmaf(xv.z, wr[kk + 2], acc);
        acc = fmaf(xv.w, wr[kk + 3], acc);
      }
      part[r][w][lane] = acc;
    }
    __syncthreads();
    for (int t = threadIdx.x; t < nrows * C1; t += 256) {
      int r = t >> 6, c = t & 63;
      float v = (part[r][0][c] + part[r][1][c]) + (part[r][2][c] + part[r][3][c]);
      xw1[(size_t)(base + r) * C1 + c] = __float2bfloat16(v);
    }
  }
}

// ---------------- layer-1 aggregation: wave per dst, padded slots ----------------
__global__ __launch_bounds__(256) void k_agg1(const int* __restrict__ pcnt, const int* __restrict__ pad,
                                              const int* __restrict__ ei, const float* __restrict__ ew,
                                              const float* __restrict__ dinv, const bf16* __restrict__ xw,
                                              const float* __restrict__ b, float* __restrict__ h, int N, int E) {
  const int lane = threadIdx.x & 63;
  const int wid = (blockIdx.x * 256 + threadIdx.x) >> 6;
  const int nw = (gridDim.x * 256) >> 6;
  for (int dst = wid; dst < N; dst += nw) {
    float dv = dinv[dst];
    float acc = fmaf(__bfloat162float(xw[(size_t)dst * C1 + lane]), dv * dv, b[lane]);  // self + bias
    int c = pcnt[dst];
    c = c < CAP ? c : CAP;
    int sv = 0;
    float nv = 0.f;
    if (lane < c) {
      int eid = pad[(size_t)dst * CAP + lane];
      sv = ei[eid];
      nv = dinv[sv] * ew[eid] * dv;  // fp32 norm
    }
    for (int k = 0; k < c; ++k) {
      int s = __shfl(sv, k);
      float nm = __shfl(nv, k);
      acc = fmaf(__bfloat162float(xw[(size_t)s * C1 + lane]), nm, acc);
    }
    h[(size_t)dst * C1 + lane] = acc;
  }
}

// ---------------- layer-1 overflow edges (atomic; ~hundreds) ----------------
__global__ __launch_bounds__(256) void k_ovf1(const int* __restrict__ ovf, const int* __restrict__ ovfn,
                                              const int* __restrict__ ei, const float* __restrict__ ew,
                                              const float* __restrict__ dinv, const bf16* __restrict__ xw,
                                              float* __restrict__ h, int E) {
  const int lane = threadIdx.x & 63;
  const int wid = (blockIdx.x * 256 + threadIdx.x) >> 6;
  const int nw = (gridDim.x * 256) >> 6;
  int n = ovfn[0];
  n = n < OVFCAP ? n : OVFCAP;
  for (int i = wid; i < n; i += nw) {
    int eid = ovf[i];
    int src = ei[eid];
    int dst = ei[E + eid];
    float nrm = dinv[src] * ew[eid] * dinv[dst];
    atomicAdd(&h[(size_t)dst * C1 + lane], __bfloat162float(xw[(size_t)src * C1 + lane]) * nrm);
  }
}

// ---------------- layer-2 aggregation: wave per dst, 32 feats x 2 edge-halves ----------------
__global__ __launch_bounds__(256) void k_agg2(const int* __restrict__ pcnt, const int* __restrict__ pad,
                                              const int* __restrict__ ei, const float* __restrict__ ew,
                                              const float* __restrict__ dinv, const float* __restrict__ xw,
                                              const float* __restrict__ b, float* __restrict__ h, int N, int E) {
  const int lane = threadIdx.x & 63;
  const int j = lane & 31, sub = lane >> 5;
  const int wid = (blockIdx.x * 256 + threadIdx.x) >> 6;
  const int nw = (gridDim.x * 256) >> 6;
  for (int dst = wid; dst < N; dst += nw) {
    float dv = dinv[dst];
    float acc = (sub == 0) ? fmaf(xw[(size_t)dst * C2 + j], dv * dv, b[j]) : 0.f;
    int c = pcnt[dst];
    c = c < CAP ? c : CAP;
    int sv = 0;
    float nv = 0.f;
    if (lane < c) {
      int eid = pad[(size_t)dst * CAP + lane];
      sv = ei[eid];
      nv = dinv[sv] * ew[eid] * dv;
    }
    for (int k = sub; k < c; k += 2) {
      int s = __shfl(sv, k);
      float nm = __shfl(nv, k);
      acc = fmaf(xw[(size_t)s * C2 + j], nm, acc);
    }
    acc += __shfl_xor(acc, 32);
    if (sub == 0) h[(size_t)dst * C2 + j] = acc;
  }
}

// ---------------- layer-2 overflow edges ----------------
__global__ __launch_bounds__(256) void k_ovf2(const int* __restrict__ ovf, const int* __restrict__ ovfn,
                                              const int* __restrict__ ei, const float* __restrict__ ew,
                                              const float* __restrict__ dinv, const float* __restrict__ xw,
                                              float* __restrict__ h, int E) {
  const int lane = threadIdx.x & 63;
  const int wid = (blockIdx.x * 256 + threadIdx.x) >> 6;
  const int nw = (gridDim.x * 256) >> 6;
  int n = ovfn[0];
  n = n < OVFCAP ? n : OVFCAP;
  for (int i = wid; i < n; i += nw) {
    int eid = ovf[i];
    int src = ei[eid];
    int dst = ei[E + eid];
    float nrm = dinv[src] * ew[eid] * dinv[dst];
    if (lane < C2) atomicAdd(&h[(size_t)dst * C2 + lane], xw[(size_t)src * C2 + lane] * nrm);
  }
}

// ---------------- BN stats: per-column sum & sumsq ----------------
template <int C>
__global__ __launch_bounds__(256) void k_bnstats(const float* __restrict__ h, float* __restrict__ stat, int N) {
  const int rpb = 256 / C;
  const int j = threadIdx.x % C;
  const int rloc = threadIdx.x / C;
  float s = 0.f, sq = 0.f;
  for (int r = blockIdx.x * rpb + rloc; r < N; r += gridDim.x * rpb) {
    float v = h[(size_t)r * C + j];
    s += v;
    sq = fmaf(v, v, sq);
  }
  __shared__ float ls[256], lq[256];
  ls[threadIdx.x] = s;
  lq[threadIdx.x] = sq;
  __syncthreads();
  if (threadIdx.x < C) {
    float ts = 0.f, tq = 0.f;
#pragma unroll
    for (int k = 0; k < rpb; ++k) {
      ts += ls[k * C + j];
      tq += lq[k * C + j];
    }
    atomicAdd(&stat[j], ts);
    atomicAdd(&stat[C + j], tq);
  }
}

template <int C>
__global__ void k_bnfinal(const float* __restrict__ stat, const float* __restrict__ g,
                          const float* __restrict__ be, float* __restrict__ ss, int N) {
  int j = threadIdx.x;
  if (j < C) {
    float inv_n = 1.0f / (float)N;
    float mean = stat[j] * inv_n;
    float var = stat[C + j] * inv_n - mean * mean;
    float sc = g[j] * rsqrtf(var + BN_EPS);
    ss[j] = sc;
    ss[C + j] = be[j] - mean * sc;
  }
}

// ---------------- BN apply + ReLU (in place) ----------------
template <int C>
__global__ __launch_bounds__(256) void k_bnapply(float* __restrict__ h, const float* __restrict__ ss, int N) {
  int total = N * C;
  for (int t = blockIdx.x * 256 + threadIdx.x; t < total; t += gridDim.x * 256) {
    int j = t % C;
    float v = fmaf(h[t], ss[j], ss[C + j]);
    h[t] = v > 0.f ? v : 0.f;
  }
}

// ---------------- xw2 = h1 @ W2 (64 -> 32), W in regs (8-way k-split) ----------------
__global__ __launch_bounds__(256) void k_gemm2(const float* __restrict__ h1, const float* __restrict__ W2,
                                               float* __restrict__ xw2, int N) {
  const int lane = threadIdx.x & 63;
  const int w = threadIdx.x >> 6;
  const int c = lane & 31, hh = lane >> 5;
  const int slice = w * 2 + hh;  // 0..7: owns k in [8*slice, 8*slice+8)
  float wr[8];
#pragma unroll
  for (int kk = 0; kk < 8; ++kk) wr[kk] = W2[(8 * slice + kk) * C2 + c];
  __shared__ float xs[R2][C1];      // 4 KB
  __shared__ float part[R2][8][C2]; // 16 KB
  for (int base = blockIdx.x * R2; base < N; base += gridDim.x * R2) {
    int nrows = min(R2, N - base);
    __syncthreads();
    for (int t = threadIdx.x; t < nrows * C1; t += 256) {
      int r = t >> 6, k = t & 63;
      xs[r][k] = h1[(size_t)(base + r) * C1 + k];
    }
    __syncthreads();
#pragma unroll 4
    for (int r = 0; r < R2; ++r) {
      if (r >= nrows) break;
      const float* xrow = &xs[r][8 * slice];
      float4 a = *(const float4*)&xrow[0];
      float4 bb = *(const float4*)&xrow[4];
      float acc = a.x * wr[0];
      acc = fmaf(a.y, wr[1], acc);
      acc = fmaf(a.z, wr[2], acc);
      acc = fmaf(a.w, wr[3], acc);
      acc = fmaf(bb.x, wr[4], acc);
      acc = fmaf(bb.y, wr[5], acc);
      acc = fmaf(bb.z, wr[6], acc);
      acc = fmaf(bb.w, wr[7], acc);
      part[r][slice][c] = acc;
    }
    __syncthreads();
    for (int t = threadIdx.x; t < nrows * C2; t += 256) {
      int r = t >> 5, cc = t & 31;
      float v = 0.f;
#pragma unroll
      for (int s = 0; s < 8; ++s) v += part[r][s][cc];
      xw2[(size_t)(base + r) * C2 + cc] = v;
    }
  }
}

// ---------------- head: out = h2 @ Wl + bl ----------------
__global__ __launch_bounds__(256) void k_head(const float* __restrict__ h2, const float* __restrict__ Wl,
                                              const float* __restrict__ bl, float* __restrict__ out, int N) {
  const int lane = threadIdx.x & 63;
  const int j = lane & 31, sub = lane >> 5;
  const int wid = (blockIdx.x * 256 + threadIdx.x) >> 6;
  const int nw = (gridDim.x * 256) >> 6;
  float wv = Wl[j];
  float blv = bl[0];
  for (int r0 = wid * 2; r0 < N; r0 += nw * 2) {
    int row = r0 + sub;
    float v = (row < N) ? h2[(size_t)row * C2 + j] * wv : 0.f;
    v += __shfl_down(v, 16, 32);
    v += __shfl_down(v, 8, 32);
    v += __shfl_down(v, 4, 32);
    v += __shfl_down(v, 2, 32);
    v += __shfl_down(v, 1, 32);
    if (j == 0 && row < N) out[row] = v + blv;
  }
}

extern "C" void kernel_launch(void* const* d_in, const int* in_sizes, int n_in,
                              void* d_out, int out_size, void* d_ws, size_t ws_size,
                              hipStream_t stream) {
  const float* x = (const float*)d_in[0];
  const int* ei = (const int*)d_in[1];  // int32 [2, E] flat
  const float* ew = (const float*)d_in[2];
  const float* W1 = (const float*)d_in[3];
  const float* b1 = (const float*)d_in[4];
  const float* g1 = (const float*)d_in[5];
  const float* be1 = (const float*)d_in[6];
  const float* W2 = (const float*)d_in[7];
  const float* b2 = (const float*)d_in[8];
  const float* g2 = (const float*)d_in[9];
  const float* be2 = (const float*)d_in[10];
  const float* Wl = (const float*)d_in[11];
  const float* bl = (const float*)d_in[12];
  float* out = (float*)d_out;

  const int N = in_sizes[0] / FIN;
  const int E = in_sizes[2];

  // workspace layout — ≈ 50.7 MB @ N=100k (< 51.6 proven)
  float* Wf = (float*)d_ws;
  float* dinv = Wf;                               // [N] f32
  int* pcnt = (int*)(Wf + N);                     // [N] i32
  int* ovfn = (int*)(Wf + 2 * (size_t)N);         // [1] i32
  float* stat1 = Wf + 2 * (size_t)N + 8;          // [128]
  float* ss1 = stat1 + 128;                       // [128]
  float* stat2 = ss1 + 128;                       // [64]
  float* ss2 = stat2 + 64;                        // [64]
  int* ovf = (int*)(Wf + 2 * (size_t)N + 512);    // [OVFCAP] i32
  int* pad = ovf + OVFCAP;                        // [N*CAP] i32
  bf16* xw1 = (bf16*)(pad + (size_t)N * CAP);     // [N*64] bf16
  float* bufB = (float*)(xw1 + (size_t)N * C1);   // [N*64] f32
  float* h1 = bufB;
  float* xw2 = (float*)xw1;                       // [N*32] f32 — exact overlay of dead xw1
  float* h2 = bufB;                               // [N*32] f32 — overlays dead h1

  // zero: dinv + pcnt + ovfn + stats
  hipMemsetAsync(Wf, 0, ((size_t)2 * N + 512) * sizeof(float), stream);

  // build padded CSR + weighted degree (fused single edge pass)
  k_degfill<<<(E + 255) / 256, 256, 0, stream>>>(ei, ew, dinv, pcnt, pad, ovf, ovfn, E);
  k_dinv<<<(N + 255) / 256, 256, 0, stream>>>(dinv, N);

  // layer 1
  k_gemm1<<<2048, 256, 0, stream>>>(x, W1, xw1, N);
  k_agg1<<<4096, 256, 0, stream>>>(pcnt, pad, ei, ew, dinv, xw1, b1, h1, N, E);
  k_ovf1<<<256, 256, 0, stream>>>(ovf, ovfn, ei, ew, dinv, xw1, h1, E);
  k_bnstats<C1><<<1024, 256, 0, stream>>>(h1, stat1, N);
  k_bnfinal<C1><<<1, C1, 0, stream>>>(stat1, g1, be1, ss1, N);
  k_bnapply<C1><<<4096, 256, 0, stream>>>(h1, ss1, N);

  // layer 2
  k_gemm2<<<2048, 256, 0, stream>>>(h1, W2, xw2, N);
  k_agg2<<<2048, 256, 0, stream>>>(pcnt, pad, ei, ew, dinv, xw2, b2, h2, N, E);
  k_ovf2<<<256, 256, 0, stream>>>(ovf, ovfn, ei, ew, dinv, xw2, h2, E);
  k_bnstats<C2><<<1024, 256, 0, stream>>>(h2, stat2, N);
  k_bnfinal<C2><<<1, C2, 0, stream>>>(stat2, g2, be2, ss2, N);
  k_bnapply<C2><<<2048, 256, 0, stream>>>(h2, ss2, N);

  // head
  k_head<<<1024, 256, 0, stream>>>(h2, Wl, bl, out, N);
}

// Round 9
// 650.749 us; speedup vs baseline: 1.5097x; 1.0190x over previous
//
#include <hip/hip_runtime.h>
#include <hip/hip_bf16.h>

#define FIN 128
#define C1 64
#define C2 32
#define BN_EPS 1e-5f
#define CAP 28       // padded CSR slots per dst
#define OVFCAP 65536 // overflow edge capacity (expected ~400 used)
#define R1 16        // rows per block-iter in gemm1
#define R2 16        // rows per block-iter in gemm2

typedef __hip_bfloat16 bf16;

// ---------------- padded CSR fill (no deg; reads only dst column of ei) ----------------
__global__ __launch_bounds__(256) void k_fillpad(const int* __restrict__ ei, int* __restrict__ pcnt,
                                                 int* __restrict__ pad, int* __restrict__ ovf,
                                                 int* __restrict__ ovfn, int E) {
  int e = blockIdx.x * 256 + threadIdx.x;
  if (e < E) {
    int dst = ei[E + e];
    int pos = atomicAdd(&pcnt[dst], 1);
    if (pos < CAP) {
      pad[(size_t)dst * CAP + pos] = e;
    } else {
      int oi = atomicAdd(ovfn, 1);
      if (oi < OVFCAP) ovf[oi] = e;
    }
  }
}

// ---------------- overflow edges' weight into deg (tiny) ----------------
__global__ __launch_bounds__(256) void k_ovfdeg(const int* __restrict__ ovf, const int* __restrict__ ovfn,
                                                const int* __restrict__ ei, const float* __restrict__ ew,
                                                float* __restrict__ deg, int E) {
  int n = ovfn[0];
  n = n < OVFCAP ? n : OVFCAP;
  for (int i = blockIdx.x * 256 + threadIdx.x; i < n; i += gridDim.x * 256) {
    int eid = ovf[i];
    atomicAdd(&deg[ei[E + eid]], ew[eid]);
  }
}

// ---------------- deg = 1 + ovfpart + sum(pad ew); dinv = rsqrt in place ----------------
__global__ __launch_bounds__(256) void k_degdinv(const int* __restrict__ pcnt, const int* __restrict__ pad,
                                                 const float* __restrict__ ew, float* __restrict__ deg, int N) {
  int i = blockIdx.x * 256 + threadIdx.x;
  if (i < N) {
    int c = pcnt[i];
    c = c < CAP ? c : CAP;
    float s = deg[i] + 1.0f;  // deg[i] holds overflow contribution (zeroed otherwise)
    const int* row = pad + (size_t)i * CAP;
    for (int k = 0; k < c; ++k) s += ew[row[k]];
    deg[i] = rsqrtf(s);
  }
}

// ---------------- xw1 = x @ W1 (128 -> 64), W in regs (k-split by wave), bf16 out ----------------
__global__ __launch_bounds__(256) void k_gemm1(const float* __restrict__ x, const float* __restrict__ W1,
                                               bf16* __restrict__ xw1, int N) {
  const int lane = threadIdx.x & 63;
  const int w = threadIdx.x >> 6;  // wave id: owns k in [32w, 32w+32)
  float wr[32];
#pragma unroll
  for (int kk = 0; kk < 32; ++kk) wr[kk] = W1[(32 * w + kk) * C1 + lane];
  __shared__ float xs[R1][FIN];      // 8 KB
  __shared__ float part[R1][4][C1];  // 16 KB
  for (int base = blockIdx.x * R1; base < N; base += gridDim.x * R1) {
    int nrows = min(R1, N - base);
    __syncthreads();  // protect xs/part from previous iteration's readers
    for (int t = threadIdx.x; t < nrows * FIN; t += 256) {
      int r = t >> 7, k = t & 127;
      xs[r][k] = x[(size_t)(base + r) * FIN + k];
    }
    __syncthreads();
#pragma unroll 4
    for (int r = 0; r < R1; ++r) {
      if (r >= nrows) break;
      const float* xrow = &xs[r][32 * w];
      float acc = 0.f;
#pragma unroll
      for (int kk = 0; kk < 32; kk += 4) {
        float4 xv = *(const float4*)&xrow[kk];  // uniform-address b128 broadcast
        acc = fmaf(xv.x, wr[kk], acc);
        acc = fmaf(xv.y, wr[kk + 1], acc);
        acc = fmaf(xv.z, wr[kk + 2], acc);
        acc = fmaf(xv.w, wr[kk + 3], acc);
      }
      part[r][w][lane] = acc;
    }
    __syncthreads();
    for (int t = threadIdx.x; t < nrows * C1; t += 256) {
      int r = t >> 6, c = t & 63;
      float v = (part[r][0][c] + part[r][1][c]) + (part[r][2][c] + part[r][3][c]);
      xw1[(size_t)(base + r) * C1 + c] = __float2bfloat16(v);
    }
  }
}

// ---------------- layer-1 aggregation: wave per dst, padded slots ----------------
__global__ __launch_bounds__(256) void k_agg1(const int* __restrict__ pcnt, const int* __restrict__ pad,
                                              const int* __restrict__ ei, const float* __restrict__ ew,
                                              const float* __restrict__ dinv, const bf16* __restrict__ xw,
                                              const float* __restrict__ b, float* __restrict__ h, int N, int E) {
  const int lane = threadIdx.x & 63;
  const int wid = (blockIdx.x * 256 + threadIdx.x) >> 6;
  const int nw = (gridDim.x * 256) >> 6;
  for (int dst = wid; dst < N; dst += nw) {
    float dv = dinv[dst];
    float acc = fmaf(__bfloat162float(xw[(size_t)dst * C1 + lane]), dv * dv, b[lane]);  // self + bias
    int c = pcnt[dst];
    c = c < CAP ? c : CAP;
    int sv = 0;
    float nv = 0.f;
    if (lane < c) {
      int eid = pad[(size_t)dst * CAP + lane];
      sv = ei[eid];
      nv = dinv[sv] * ew[eid] * dv;  // fp32 norm
    }
    for (int k = 0; k < c; ++k) {
      int s = __shfl(sv, k);
      float nm = __shfl(nv, k);
      acc = fmaf(__bfloat162float(xw[(size_t)s * C1 + lane]), nm, acc);
    }
    h[(size_t)dst * C1 + lane] = acc;
  }
}

// ---------------- layer-1 overflow edges (atomic; ~hundreds) ----------------
__global__ __launch_bounds__(256) void k_ovf1(const int* __restrict__ ovf, const int* __restrict__ ovfn,
                                              const int* __restrict__ ei, const float* __restrict__ ew,
                                              const float* __restrict__ dinv, const bf16* __restrict__ xw,
                                              float* __restrict__ h, int E) {
  const int lane = threadIdx.x & 63;
  const int wid = (blockIdx.x * 256 + threadIdx.x) >> 6;
  const int nw = (gridDim.x * 256) >> 6;
  int n = ovfn[0];
  n = n < OVFCAP ? n : OVFCAP;
  for (int i = wid; i < n; i += nw) {
    int eid = ovf[i];
    int src = ei[eid];
    int dst = ei[E + eid];
    float nrm = dinv[src] * ew[eid] * dinv[dst];
    atomicAdd(&h[(size_t)dst * C1 + lane], __bfloat162float(xw[(size_t)src * C1 + lane]) * nrm);
  }
}

// ---------------- layer-2 aggregation: wave per dst, 32 feats x 2 edge-halves ----------------
__global__ __launch_bounds__(256) void k_agg2(const int* __restrict__ pcnt, const int* __restrict__ pad,
                                              const int* __restrict__ ei, const float* __restrict__ ew,
                                              const float* __restrict__ dinv, const float* __restrict__ xw,
                                              const float* __restrict__ b, float* __restrict__ h, int N, int E) {
  const int lane = threadIdx.x & 63;
  const int j = lane & 31, sub = lane >> 5;
  const int wid = (blockIdx.x * 256 + threadIdx.x) >> 6;
  const int nw = (gridDim.x * 256) >> 6;
  for (int dst = wid; dst < N; dst += nw) {
    float dv = dinv[dst];
    float acc = (sub == 0) ? fmaf(xw[(size_t)dst * C2 + j], dv * dv, b[j]) : 0.f;
    int c = pcnt[dst];
    c = c < CAP ? c : CAP;
    int sv = 0;
    float nv = 0.f;
    if (lane < c) {
      int eid = pad[(size_t)dst * CAP + lane];
      sv = ei[eid];
      nv = dinv[sv] * ew[eid] * dv;
    }
    for (int k = sub; k < c; k += 2) {
      int s = __shfl(sv, k);
      float nm = __shfl(nv, k);
      acc = fmaf(xw[(size_t)s * C2 + j], nm, acc);
    }
    acc += __shfl_xor(acc, 32);
    if (sub == 0) h[(size_t)dst * C2 + j] = acc;
  }
}

// ---------------- layer-2 overflow edges ----------------
__global__ __launch_bounds__(256) void k_ovf2(const int* __restrict__ ovf, const int* __restrict__ ovfn,
                                              const int* __restrict__ ei, const float* __restrict__ ew,
                                              const float* __restrict__ dinv, const float* __restrict__ xw,
                                              float* __restrict__ h, int E) {
  const int lane = threadIdx.x & 63;
  const int wid = (blockIdx.x * 256 + threadIdx.x) >> 6;
  const int nw = (gridDim.x * 256) >> 6;
  int n = ovfn[0];
  n = n < OVFCAP ? n : OVFCAP;
  for (int i = wid; i < n; i += nw) {
    int eid = ovf[i];
    int src = ei[eid];
    int dst = ei[E + eid];
    float nrm = dinv[src] * ew[eid] * dinv[dst];
    if (lane < C2) atomicAdd(&h[(size_t)dst * C2 + lane], xw[(size_t)src * C2 + lane] * nrm);
  }
}

// ---------------- BN stats: per-column sum & sumsq ----------------
template <int C>
__global__ __launch_bounds__(256) void k_bnstats(const float* __restrict__ h, float* __restrict__ stat, int N) {
  const int rpb = 256 / C;
  const int j = threadIdx.x % C;
  const int rloc = threadIdx.x / C;
  float s = 0.f, sq = 0.f;
  for (int r = blockIdx.x * rpb + rloc; r < N; r += gridDim.x * rpb) {
    float v = h[(size_t)r * C + j];
    s += v;
    sq = fmaf(v, v, sq);
  }
  __shared__ float ls[256], lq[256];
  ls[threadIdx.x] = s;
  lq[threadIdx.x] = sq;
  __syncthreads();
  if (threadIdx.x < C) {
    float ts = 0.f, tq = 0.f;
#pragma unroll
    for (int k = 0; k < rpb; ++k) {
      ts += ls[k * C + j];
      tq += lq[k * C + j];
    }
    atomicAdd(&stat[j], ts);
    atomicAdd(&stat[C + j], tq);
  }
}

template <int C>
__global__ void k_bnfinal(const float* __restrict__ stat, const float* __restrict__ g,
                          const float* __restrict__ be, float* __restrict__ ss, int N) {
  int j = threadIdx.x;
  if (j < C) {
    float inv_n = 1.0f / (float)N;
    float mean = stat[j] * inv_n;
    float var = stat[C + j] * inv_n - mean * mean;
    float sc = g[j] * rsqrtf(var + BN_EPS);
    ss[j] = sc;
    ss[C + j] = be[j] - mean * sc;
  }
}

// ---------------- xw2 = relu(bn(h1raw)) @ W2 (64 -> 32), BN1 fused, W in regs ----------------
__global__ __launch_bounds__(256) void k_gemm2(const float* __restrict__ h1, const float* __restrict__ ss,
                                               const float* __restrict__ W2, float* __restrict__ xw2, int N) {
  const int lane = threadIdx.x & 63;
  const int w = threadIdx.x >> 6;
  const int c = lane & 31, hh = lane >> 5;
  const int slice = w * 2 + hh;  // 0..7: owns k in [8*slice, 8*slice+8)
  float wr[8];
#pragma unroll
  for (int kk = 0; kk < 8; ++kk) wr[kk] = W2[(8 * slice + kk) * C2 + c];
  __shared__ float sss[2 * C1];  // BN1 scale/shift
  if (threadIdx.x < 2 * C1) sss[threadIdx.x] = ss[threadIdx.x];
  __shared__ float xs[R2][C1];      // 4 KB
  __shared__ float part[R2][8][C2]; // 16 KB
  for (int base = blockIdx.x * R2; base < N; base += gridDim.x * R2) {
    int nrows = min(R2, N - base);
    __syncthreads();
    for (int t = threadIdx.x; t < nrows * C1; t += 256) {
      int r = t >> 6, k = t & 63;
      float v = fmaf(h1[(size_t)(base + r) * C1 + k], sss[k], sss[C1 + k]);
      xs[r][k] = v > 0.f ? v : 0.f;
    }
    __syncthreads();
#pragma unroll 4
    for (int r = 0; r < R2; ++r) {
      if (r >= nrows) break;
      const float* xrow = &xs[r][8 * slice];
      float4 a = *(const float4*)&xrow[0];
      float4 bb = *(const float4*)&xrow[4];
      float acc = a.x * wr[0];
      acc = fmaf(a.y, wr[1], acc);
      acc = fmaf(a.z, wr[2], acc);
      acc = fmaf(a.w, wr[3], acc);
      acc = fmaf(bb.x, wr[4], acc);
      acc = fmaf(bb.y, wr[5], acc);
      acc = fmaf(bb.z, wr[6], acc);
      acc = fmaf(bb.w, wr[7], acc);
      part[r][slice][c] = acc;
    }
    __syncthreads();
    for (int t = threadIdx.x; t < nrows * C2; t += 256) {
      int r = t >> 5, cc = t & 31;
      float v = 0.f;
#pragma unroll
      for (int s = 0; s < 8; ++s) v += part[r][s][cc];
      xw2[(size_t)(base + r) * C2 + cc] = v;
    }
  }
}

// ---------------- head: out = relu(bn(h2raw)) @ Wl + bl, BN2 fused ----------------
__global__ __launch_bounds__(256) void k_head(const float* __restrict__ h2, const float* __restrict__ ss,
                                              const float* __restrict__ Wl, const float* __restrict__ bl,
                                              float* __restrict__ out, int N) {
  const int lane = threadIdx.x & 63;
  const int j = lane & 31, sub = lane >> 5;
  const int wid = (blockIdx.x * 256 + threadIdx.x) >> 6;
  const int nw = (gridDim.x * 256) >> 6;
  const float sc = ss[j], sh = ss[C2 + j];
  const float wv = Wl[j];
  const float blv = bl[0];
  for (int r0 = wid * 2; r0 < N; r0 += nw * 2) {
    int row = r0 + sub;
    float v = 0.f;
    if (row < N) {
      float hh = fmaf(h2[(size_t)row * C2 + j], sc, sh);
      hh = hh > 0.f ? hh : 0.f;
      v = hh * wv;
    }
    v += __shfl_down(v, 16, 32);
    v += __shfl_down(v, 8, 32);
    v += __shfl_down(v, 4, 32);
    v += __shfl_down(v, 2, 32);
    v += __shfl_down(v, 1, 32);
    if (j == 0 && row < N) out[row] = v + blv;
  }
}

extern "C" void kernel_launch(void* const* d_in, const int* in_sizes, int n_in,
                              void* d_out, int out_size, void* d_ws, size_t ws_size,
                              hipStream_t stream) {
  const float* x = (const float*)d_in[0];
  const int* ei = (const int*)d_in[1];  // int32 [2, E] flat
  const float* ew = (const float*)d_in[2];
  const float* W1 = (const float*)d_in[3];
  const float* b1 = (const float*)d_in[4];
  const float* g1 = (const float*)d_in[5];
  const float* be1 = (const float*)d_in[6];
  const float* W2 = (const float*)d_in[7];
  const float* b2 = (const float*)d_in[8];
  const float* g2 = (const float*)d_in[9];
  const float* be2 = (const float*)d_in[10];
  const float* Wl = (const float*)d_in[11];
  const float* bl = (const float*)d_in[12];
  float* out = (float*)d_out;

  const int N = in_sizes[0] / FIN;
  const int E = in_sizes[2];

  // workspace layout — ≈ 50.7 MB @ N=100k (< 51.6 proven)
  float* Wf = (float*)d_ws;
  float* dinv = Wf;                               // [N] f32 (deg accum -> dinv)
  int* pcnt = (int*)(Wf + N);                     // [N] i32
  int* ovfn = (int*)(Wf + 2 * (size_t)N);         // [1] i32
  float* stat1 = Wf + 2 * (size_t)N + 8;          // [128]
  float* ss1 = stat1 + 128;                       // [128]
  float* stat2 = ss1 + 128;                       // [64]
  float* ss2 = stat2 + 64;                        // [64]
  int* ovf = (int*)(Wf + 2 * (size_t)N + 512);    // [OVFCAP] i32
  int* pad = ovf + OVFCAP;                        // [N*CAP] i32
  bf16* xw1 = (bf16*)(pad + (size_t)N * CAP);     // [N*64] bf16
  float* bufB = (float*)(xw1 + (size_t)N * C1);   // [N*64] f32
  float* h1 = bufB;
  float* xw2 = (float*)xw1;                       // [N*32] f32 — exact overlay of dead xw1
  float* h2 = bufB;                               // [N*32] f32 — overlays dead h1

  // zero: deg + pcnt + ovfn + stats
  hipMemsetAsync(Wf, 0, ((size_t)2 * N + 512) * sizeof(float), stream);

  // padded CSR build; deg from pad afterwards (no deg atomics in the big pass)
  k_fillpad<<<(E + 255) / 256, 256, 0, stream>>>(ei, pcnt, pad, ovf, ovfn, E);
  k_ovfdeg<<<16, 256, 0, stream>>>(ovf, ovfn, ei, ew, dinv, E);
  k_degdinv<<<(N + 255) / 256, 256, 0, stream>>>(pcnt, pad, ew, dinv, N);

  // layer 1
  k_gemm1<<<2048, 256, 0, stream>>>(x, W1, xw1, N);
  k_agg1<<<4096, 256, 0, stream>>>(pcnt, pad, ei, ew, dinv, xw1, b1, h1, N, E);
  k_ovf1<<<256, 256, 0, stream>>>(ovf, ovfn, ei, ew, dinv, xw1, h1, E);
  k_bnstats<C1><<<1024, 256, 0, stream>>>(h1, stat1, N);
  k_bnfinal<C1><<<1, C1, 0, stream>>>(stat1, g1, be1, ss1, N);

  // layer 2 (BN1 fused into gemm2)
  k_gemm2<<<2048, 256, 0, stream>>>(h1, ss1, W2, xw2, N);
  k_agg2<<<2048, 256, 0, stream>>>(pcnt, pad, ei, ew, dinv, xw2, b2, h2, N, E);
  k_ovf2<<<256, 256, 0, stream>>>(ovf, ovfn, ei, ew, dinv, xw2, h2, E);
  k_bnstats<C2><<<1024, 256, 0, stream>>>(h2, stat2, N);
  k_bnfinal<C2><<<1, C2, 0, stream>>>(stat2, g2, be2, ss2, N);

  // head (BN2 fused)
  k_head<<<1024, 256, 0, stream>>>(h2, ss2, Wl, bl, out, N);
}

// Round 10
// 571.062 us; speedup vs baseline: 1.7204x; 1.1395x over previous
//
#include <hip/hip_runtime.h>
#include <hip/hip_bf16.h>

#define FIN 128
#define C1 64
#define C2 32
#define BN_EPS 1e-5f
#define CAP 28       // padded CSR slots per dst
#define OVFCAP 65536 // overflow edge capacity (expected ~400 used)
#define R1 16        // rows per block-iter in gemm1
#define R2 16        // rows per block-iter in gemm2
#define GF 512       // fill-role blocks (64 per dst-range group x 8 groups)
#define GG 1024      // gemm-role blocks

typedef __hip_bfloat16 bf16;

// ---------------- fused: XCD-partitioned padded-CSR fill || xw1 = x @ W1 ----------------
// fill role (blockIdx < GF): group g = blockIdx&7 owns dst range [gN/8,(g+1)N/8) -> each
//   pad/pcnt cache line has a single-XCD writer (round-robin blockIdx%8 -> XCD).
// gemm role: W1 in regs (k-split by wave), rows staged in LDS, bf16 out.
__global__ __launch_bounds__(256) void k_fill_gemm1(const int* __restrict__ ei, int* __restrict__ pcnt,
                                                    int* __restrict__ pad, int* __restrict__ ovf,
                                                    int* __restrict__ ovfn,
                                                    const float* __restrict__ x, const float* __restrict__ W1,
                                                    bf16* __restrict__ xw1, int N, int E) {
  __shared__ float xs[R1][FIN];      // 8 KB (gemm role only)
  __shared__ float part[R1][4][C1];  // 16 KB
  if (blockIdx.x < GF) {
    // ---- fill role ----
    const int g = blockIdx.x & 7;
    const int sub = blockIdx.x >> 3;   // 0..GF/8-1
    const int nsub = GF >> 3;
    const int lo = (int)(((long long)N * g) >> 3);
    const int hi = (int)(((long long)N * (g + 1)) >> 3);
    for (int e = sub * 256 + threadIdx.x; e < E; e += nsub * 256) {
      int dst = ei[E + e];
      if (dst >= lo && dst < hi) {
        int pos = atomicAdd(&pcnt[dst], 1);
        if (pos < CAP) {
          pad[(size_t)dst * CAP + pos] = e;
        } else {
          int oi = atomicAdd(ovfn, 1);
          if (oi < OVFCAP) ovf[oi] = e;
        }
      }
    }
  } else {
    // ---- gemm role ----
    const int bg = blockIdx.x - GF;
    const int lane = threadIdx.x & 63;
    const int w = threadIdx.x >> 6;  // wave id: owns k in [32w, 32w+32)
    float wr[32];
#pragma unroll
    for (int kk = 0; kk < 32; ++kk) wr[kk] = W1[(32 * w + kk) * C1 + lane];
    for (int base = bg * R1; base < N; base += GG * R1) {
      int nrows = min(R1, N - base);
      __syncthreads();  // protect xs/part from previous iteration's readers
      for (int t = threadIdx.x; t < nrows * FIN; t += 256) {
        int r = t >> 7, k = t & 127;
        xs[r][k] = x[(size_t)(base + r) * FIN + k];
      }
      __syncthreads();
#pragma unroll 4
      for (int r = 0; r < R1; ++r) {
        if (r >= nrows) break;
        const float* xrow = &xs[r][32 * w];
        float acc = 0.f;
#pragma unroll
        for (int kk = 0; kk < 32; kk += 4) {
          float4 xv = *(const float4*)&xrow[kk];  // uniform-address b128 broadcast
          acc = fmaf(xv.x, wr[kk], acc);
          acc = fmaf(xv.y, wr[kk + 1], acc);
          acc = fmaf(xv.z, wr[kk + 2], acc);
          acc = fmaf(xv.w, wr[kk + 3], acc);
        }
        part[r][w][lane] = acc;
      }
      __syncthreads();
      for (int t = threadIdx.x; t < nrows * C1; t += 256) {
        int r = t >> 6, c = t & 63;
        float v = (part[r][0][c] + part[r][1][c]) + (part[r][2][c] + part[r][3][c]);
        xw1[(size_t)(base + r) * C1 + c] = __float2bfloat16(v);
      }
    }
  }
}

// ---------------- overflow edges' weight into deg (tiny) ----------------
__global__ __launch_bounds__(256) void k_ovfdeg(const int* __restrict__ ovf, const int* __restrict__ ovfn,
                                                const int* __restrict__ ei, const float* __restrict__ ew,
                                                float* __restrict__ deg, int E) {
  int n = ovfn[0];
  n = n < OVFCAP ? n : OVFCAP;
  for (int i = blockIdx.x * 256 + threadIdx.x; i < n; i += gridDim.x * 256) {
    int eid = ovf[i];
    atomicAdd(&deg[ei[E + eid]], ew[eid]);
  }
}

// ---------------- deg = 1 + ovfpart + sum(pad ew); dinv = rsqrt in place ----------------
__global__ __launch_bounds__(256) void k_degdinv(const int* __restrict__ pcnt, const int* __restrict__ pad,
                                                 const float* __restrict__ ew, float* __restrict__ deg, int N) {
  int i = blockIdx.x * 256 + threadIdx.x;
  if (i < N) {
    int c = pcnt[i];
    c = c < CAP ? c : CAP;
    float s = deg[i] + 1.0f;  // deg[i] holds overflow contribution (zeroed otherwise)
    const int* row = pad + (size_t)i * CAP;
    for (int k = 0; k < c; ++k) s += ew[row[k]];
    deg[i] = rsqrtf(s);
  }
}

// ---------------- layer-1 aggregation: wave per dst, padded slots ----------------
__global__ __launch_bounds__(256) void k_agg1(const int* __restrict__ pcnt, const int* __restrict__ pad,
                                              const int* __restrict__ ei, const float* __restrict__ ew,
                                              const float* __restrict__ dinv, const bf16* __restrict__ xw,
                                              const float* __restrict__ b, float* __restrict__ h, int N, int E) {
  const int lane = threadIdx.x & 63;
  const int wid = (blockIdx.x * 256 + threadIdx.x) >> 6;
  const int nw = (gridDim.x * 256) >> 6;
  for (int dst = wid; dst < N; dst += nw) {
    float dv = dinv[dst];
    float acc = fmaf(__bfloat162float(xw[(size_t)dst * C1 + lane]), dv * dv, b[lane]);  // self + bias
    int c = pcnt[dst];
    c = c < CAP ? c : CAP;
    int sv = 0;
    float nv = 0.f;
    if (lane < c) {
      int eid = pad[(size_t)dst * CAP + lane];
      sv = ei[eid];
      nv = dinv[sv] * ew[eid] * dv;  // fp32 norm
    }
    for (int k = 0; k < c; ++k) {
      int s = __shfl(sv, k);
      float nm = __shfl(nv, k);
      acc = fmaf(__bfloat162float(xw[(size_t)s * C1 + lane]), nm, acc);
    }
    h[(size_t)dst * C1 + lane] = acc;
  }
}

// ---------------- layer-1 overflow edges (atomic; ~hundreds) ----------------
__global__ __launch_bounds__(256) void k_ovf1(const int* __restrict__ ovf, const int* __restrict__ ovfn,
                                              const int* __restrict__ ei, const float* __restrict__ ew,
                                              const float* __restrict__ dinv, const bf16* __restrict__ xw,
                                              float* __restrict__ h, int E) {
  const int lane = threadIdx.x & 63;
  const int wid = (blockIdx.x * 256 + threadIdx.x) >> 6;
  const int nw = (gridDim.x * 256) >> 6;
  int n = ovfn[0];
  n = n < OVFCAP ? n : OVFCAP;
  for (int i = wid; i < n; i += nw) {
    int eid = ovf[i];
    int src = ei[eid];
    int dst = ei[E + eid];
    float nrm = dinv[src] * ew[eid] * dinv[dst];
    atomicAdd(&h[(size_t)dst * C1 + lane], __bfloat162float(xw[(size_t)src * C1 + lane]) * nrm);
  }
}

// ---------------- layer-2 aggregation: wave per dst, 32 feats x 2 edge-halves ----------------
__global__ __launch_bounds__(256) void k_agg2(const int* __restrict__ pcnt, const int* __restrict__ pad,
                                              const int* __restrict__ ei, const float* __restrict__ ew,
                                              const float* __restrict__ dinv, const float* __restrict__ xw,
                                              const float* __restrict__ b, float* __restrict__ h, int N, int E) {
  const int lane = threadIdx.x & 63;
  const int j = lane & 31, sub = lane >> 5;
  const int wid = (blockIdx.x * 256 + threadIdx.x) >> 6;
  const int nw = (gridDim.x * 256) >> 6;
  for (int dst = wid; dst < N; dst += nw) {
    float dv = dinv[dst];
    float acc = (sub == 0) ? fmaf(xw[(size_t)dst * C2 + j], dv * dv, b[j]) : 0.f;
    int c = pcnt[dst];
    c = c < CAP ? c : CAP;
    int sv = 0;
    float nv = 0.f;
    if (lane < c) {
      int eid = pad[(size_t)dst * CAP + lane];
      sv = ei[eid];
      nv = dinv[sv] * ew[eid] * dv;
    }
    for (int k = sub; k < c; k += 2) {
      int s = __shfl(sv, k);
      float nm = __shfl(nv, k);
      acc = fmaf(xw[(size_t)s * C2 + j], nm, acc);
    }
    acc += __shfl_xor(acc, 32);
    if (sub == 0) h[(size_t)dst * C2 + j] = acc;
  }
}

// ---------------- layer-2 overflow edges ----------------
__global__ __launch_bounds__(256) void k_ovf2(const int* __restrict__ ovf, const int* __restrict__ ovfn,
                                              const int* __restrict__ ei, const float* __restrict__ ew,
                                              const float* __restrict__ dinv, const float* __restrict__ xw,
                                              float* __restrict__ h, int E) {
  const int lane = threadIdx.x & 63;
  const int wid = (blockIdx.x * 256 + threadIdx.x) >> 6;
  const int nw = (gridDim.x * 256) >> 6;
  int n = ovfn[0];
  n = n < OVFCAP ? n : OVFCAP;
  for (int i = wid; i < n; i += nw) {
    int eid = ovf[i];
    int src = ei[eid];
    int dst = ei[E + eid];
    float nrm = dinv[src] * ew[eid] * dinv[dst];
    if (lane < C2) atomicAdd(&h[(size_t)dst * C2 + lane], xw[(size_t)src * C2 + lane] * nrm);
  }
}

// ---------------- BN stats: per-column sum & sumsq ----------------
template <int C>
__global__ __launch_bounds__(256) void k_bnstats(const float* __restrict__ h, float* __restrict__ stat, int N) {
  const int rpb = 256 / C;
  const int j = threadIdx.x % C;
  const int rloc = threadIdx.x / C;
  float s = 0.f, sq = 0.f;
  for (int r = blockIdx.x * rpb + rloc; r < N; r += gridDim.x * rpb) {
    float v = h[(size_t)r * C + j];
    s += v;
    sq = fmaf(v, v, sq);
  }
  __shared__ float ls[256], lq[256];
  ls[threadIdx.x] = s;
  lq[threadIdx.x] = sq;
  __syncthreads();
  if (threadIdx.x < C) {
    float ts = 0.f, tq = 0.f;
#pragma unroll
    for (int k = 0; k < rpb; ++k) {
      ts += ls[k * C + j];
      tq += lq[k * C + j];
    }
    atomicAdd(&stat[j], ts);
    atomicAdd(&stat[C + j], tq);
  }
}

// ---------------- xw2 = relu(bn(h1raw)) @ W2 (64 -> 32), BN1 finalized inline, W in regs ----------------
__global__ __launch_bounds__(256) void k_gemm2(const float* __restrict__ h1, const float* __restrict__ stat,
                                               const float* __restrict__ g, const float* __restrict__ be,
                                               const float* __restrict__ W2, float* __restrict__ xw2, int N) {
  const int lane = threadIdx.x & 63;
  const int w = threadIdx.x >> 6;
  const int c = lane & 31, hh = lane >> 5;
  const int slice = w * 2 + hh;  // 0..7: owns k in [8*slice, 8*slice+8)
  float wr[8];
#pragma unroll
  for (int kk = 0; kk < 8; ++kk) wr[kk] = W2[(8 * slice + kk) * C2 + c];
  __shared__ float sss[2 * C1];  // BN1 scale/shift, computed from stats per block
  if (threadIdx.x < C1) {
    float inv_n = 1.0f / (float)N;
    float mean = stat[threadIdx.x] * inv_n;
    float var = stat[C1 + threadIdx.x] * inv_n - mean * mean;
    float sc = g[threadIdx.x] * rsqrtf(var + BN_EPS);
    sss[threadIdx.x] = sc;
    sss[C1 + threadIdx.x] = be[threadIdx.x] - mean * sc;
  }
  __shared__ float xs[R2][C1];      // 4 KB
  __shared__ float part[R2][8][C2]; // 16 KB
  for (int base = blockIdx.x * R2; base < N; base += gridDim.x * R2) {
    int nrows = min(R2, N - base);
    __syncthreads();  // also covers sss readiness on first iteration
    for (int t = threadIdx.x; t < nrows * C1; t += 256) {
      int r = t >> 6, k = t & 63;
      float v = fmaf(h1[(size_t)(base + r) * C1 + k], sss[k], sss[C1 + k]);
      xs[r][k] = v > 0.f ? v : 0.f;
    }
    __syncthreads();
#pragma unroll 4
    for (int r = 0; r < R2; ++r) {
      if (r >= nrows) break;
      const float* xrow = &xs[r][8 * slice];
      float4 a = *(const float4*)&xrow[0];
      float4 bb = *(const float4*)&xrow[4];
      float acc = a.x * wr[0];
      acc = fmaf(a.y, wr[1], acc);
      acc = fmaf(a.z, wr[2], acc);
      acc = fmaf(a.w, wr[3], acc);
      acc = fmaf(bb.x, wr[4], acc);
      acc = fmaf(bb.y, wr[5], acc);
      acc = fmaf(bb.z, wr[6], acc);
      acc = fmaf(bb.w, wr[7], acc);
      part[r][slice][c] = acc;
    }
    __syncthreads();
    for (int t = threadIdx.x; t < nrows * C2; t += 256) {
      int r = t >> 5, cc = t & 31;
      float v = 0.f;
#pragma unroll
      for (int s = 0; s < 8; ++s) v += part[r][s][cc];
      xw2[(size_t)(base + r) * C2 + cc] = v;
    }
  }
}

// ---------------- head: out = relu(bn(h2raw)) @ Wl + bl, BN2 finalized inline ----------------
__global__ __launch_bounds__(256) void k_head(const float* __restrict__ h2, const float* __restrict__ stat,
                                              const float* __restrict__ g, const float* __restrict__ be,
                                              const float* __restrict__ Wl, const float* __restrict__ bl,
                                              float* __restrict__ out, int N) {
  const int lane = threadIdx.x & 63;
  const int j = lane & 31, sub = lane >> 5;
  const int wid = (blockIdx.x * 256 + threadIdx.x) >> 6;
  const int nw = (gridDim.x * 256) >> 6;
  const float inv_n = 1.0f / (float)N;
  const float mean = stat[j] * inv_n;
  const float var = stat[C2 + j] * inv_n - mean * mean;
  const float sc = g[j] * rsqrtf(var + BN_EPS);
  const float sh = be[j] - mean * sc;
  const float wv = Wl[j];
  const float blv = bl[0];
  for (int r0 = wid * 2; r0 < N; r0 += nw * 2) {
    int row = r0 + sub;
    float v = 0.f;
    if (row < N) {
      float hh = fmaf(h2[(size_t)row * C2 + j], sc, sh);
      hh = hh > 0.f ? hh : 0.f;
      v = hh * wv;
    }
    v += __shfl_down(v, 16, 32);
    v += __shfl_down(v, 8, 32);
    v += __shfl_down(v, 4, 32);
    v += __shfl_down(v, 2, 32);
    v += __shfl_down(v, 1, 32);
    if (j == 0 && row < N) out[row] = v + blv;
  }
}

extern "C" void kernel_launch(void* const* d_in, const int* in_sizes, int n_in,
                              void* d_out, int out_size, void* d_ws, size_t ws_size,
                              hipStream_t stream) {
  const float* x = (const float*)d_in[0];
  const int* ei = (const int*)d_in[1];  // int32 [2, E] flat
  const float* ew = (const float*)d_in[2];
  const float* W1 = (const float*)d_in[3];
  const float* b1 = (const float*)d_in[4];
  const float* g1 = (const float*)d_in[5];
  const float* be1 = (const float*)d_in[6];
  const float* W2 = (const float*)d_in[7];
  const float* b2 = (const float*)d_in[8];
  const float* g2 = (const float*)d_in[9];
  const float* be2 = (const float*)d_in[10];
  const float* Wl = (const float*)d_in[11];
  const float* bl = (const float*)d_in[12];
  float* out = (float*)d_out;

  const int N = in_sizes[0] / FIN;
  const int E = in_sizes[2];

  // workspace layout — ≈ 50.7 MB @ N=100k (< 51.6 proven)
  float* Wf = (float*)d_ws;
  float* dinv = Wf;                               // [N] f32 (deg accum -> dinv)
  int* pcnt = (int*)(Wf + N);                     // [N] i32
  int* ovfn = (int*)(Wf + 2 * (size_t)N);         // [1] i32
  float* stat1 = Wf + 2 * (size_t)N + 8;          // [128]
  float* stat2 = stat1 + 128;                     // [64]
  int* ovf = (int*)(Wf + 2 * (size_t)N + 512);    // [OVFCAP] i32
  int* pad = ovf + OVFCAP;                        // [N*CAP] i32
  bf16* xw1 = (bf16*)(pad + (size_t)N * CAP);     // [N*64] bf16
  float* bufB = (float*)(xw1 + (size_t)N * C1);   // [N*64] f32
  float* h1 = bufB;
  float* xw2 = (float*)xw1;                       // [N*32] f32 — exact overlay of dead xw1
  float* h2 = bufB;                               // [N*32] f32 — overlays dead h1

  // zero: deg + pcnt + ovfn + stats
  hipMemsetAsync(Wf, 0, ((size_t)2 * N + 512) * sizeof(float), stream);

  // fused: XCD-partitioned padded-CSR build || gemm1
  k_fill_gemm1<<<GF + GG, 256, 0, stream>>>(ei, pcnt, pad, ovf, ovfn, x, W1, xw1, N, E);
  k_ovfdeg<<<16, 256, 0, stream>>>(ovf, ovfn, ei, ew, dinv, E);
  k_degdinv<<<(N + 255) / 256, 256, 0, stream>>>(pcnt, pad, ew, dinv, N);

  // layer 1
  k_agg1<<<4096, 256, 0, stream>>>(pcnt, pad, ei, ew, dinv, xw1, b1, h1, N, E);
  k_ovf1<<<256, 256, 0, stream>>>(ovf, ovfn, ei, ew, dinv, xw1, h1, E);
  k_bnstats<C1><<<1024, 256, 0, stream>>>(h1, stat1, N);

  // layer 2 (BN1 finalized inside gemm2)
  k_gemm2<<<2048, 256, 0, stream>>>(h1, stat1, g1, be1, W2, xw2, N);
  k_agg2<<<2048, 256, 0, stream>>>(pcnt, pad, ei, ew, dinv, xw2, b2, h2, N, E);
  k_ovf2<<<256, 256, 0, stream>>>(ovf, ovfn, ei, ew, dinv, xw2, h2, E);
  k_bnstats<C2><<<1024, 256, 0, stream>>>(h2, stat2, N);

  // head (BN2 finalized inline)
  k_head<<<1024, 256, 0, stream>>>(h2, stat2, g2, be2, Wl, bl, out, N);
}